// Round 6
// baseline (159.222 us; speedup 1.0000x reference)
//
#include <hip/hip_runtime.h>
#include <hip/hip_bf16.h>

// ---------------------------------------------------------------------------
// MultiHeadAttention forward on MI355X (gfx950). B=2,S=2048,D=768,H=12,Dh=64.
// Masks scale by +1e-9 (numeric no-op) -> full non-causal softmax; dropped.
//
// Round 6: attention occupancy attack. Round-5 counters showed attn at 25%
// occupancy (grid 768 = 3 blocks/CU), MFMA 39 + VALU 38 = 77% combined, dur
// unchanged by the VALU diet -> wave-starved, not pipe-bound. Key-split x2:
// grid (32,24,2)=1536 blocks, 64-key tiles (16 KB LDS -> 6 blocks/CU all
// co-resident = 75% occupancy). f32 partial O + partial denom, tiny combine
// kernel -> bf16 ctx.
// ---------------------------------------------------------------------------

typedef __attribute__((ext_vector_type(8))) short short8;
typedef __attribute__((ext_vector_type(4))) float float4v;
typedef __attribute__((ext_vector_type(8))) _Float16 half8;
typedef __attribute__((ext_vector_type(4))) _Float16 half4;
typedef __attribute__((ext_vector_type(4))) unsigned short ushort4v;

__device__ __forceinline__ void async_copy16(const void* g, void* l) {
  __builtin_amdgcn_global_load_lds(
      (const __attribute__((address_space(1))) void*)g,
      (__attribute__((address_space(3))) void*)l, 16, 0, 0);
}

__device__ __forceinline__ float fast_exp2(float x) {
#if __has_builtin(__builtin_amdgcn_exp2f)
  return __builtin_amdgcn_exp2f(x);
#else
  return exp2f(x);
#endif
}

__device__ __forceinline__ unsigned short f2bf(float v) {
  __hip_bfloat16 h = __float2bfloat16(v);
  unsigned short u;
  __builtin_memcpy(&u, &h, 2);
  return u;
}

#define LOG2E_8 0.18033688011112042f  // log2(e)/8, folded into Q

// ---- fused prep: x f32->bf16 cast; w_qkv, w_proj transpose->bf16 -----------
__global__ __launch_bounds__(256) void k_prep(
    const float* __restrict__ x, unsigned short* __restrict__ xb,
    const float* __restrict__ wqkv, __hip_bfloat16* __restrict__ wqkvT,
    const float* __restrict__ wproj, __hip_bfloat16* __restrict__ wprojT) {
  __shared__ float tile[32][33];
  const int bid = blockIdx.x, tid = threadIdx.x;
  if (bid < 3072) {  // cast: 4096*768 floats, 4/thread
    int i = bid * 256 + tid;
    float4v v = ((const float4v*)x)[i];
    ushort4v o;
#pragma unroll
    for (int r = 0; r < 4; r++) o[r] = f2bf(v[r]);
    ((ushort4v*)xb)[i] = o;
    return;
  }
  const float* w;
  __hip_bfloat16* wt;
  int N, bx, by;
  if (bid < 4800) {
    int t = bid - 3072; w = wqkv; wt = wqkvT; N = 2304; bx = t % 72; by = t / 72;
  } else {
    int t = bid - 4800; w = wproj; wt = wprojT; N = 768; bx = t % 24; by = t / 24;
  }
  const int n0 = bx * 32, k0 = by * 32;
  const int r = tid >> 5, c = tid & 31;
#pragma unroll
  for (int rr = 0; rr < 32; rr += 8)
    tile[rr + r][c] = w[(long long)(k0 + rr + r) * N + n0 + c];
  __syncthreads();
#pragma unroll
  for (int rr = 0; rr < 32; rr += 8)
    wt[(long long)(n0 + rr + r) * 768 + k0 + c] = __float2bfloat16(tile[c][rr + r]);
}

// ---- bf16 GEMM, BK=64, K=768 (12 iters), conflict-free XOR swizzle ---------
// EPI==0: 128x96 tile; scatter Q(prescaled),K->[B,H,S,64] f16, V->VT (+bias).
// EPI==1: 64x64 tile; out f32 [M][768] = acc + bias.
template <int EPI>
__global__ __launch_bounds__(256) void k_gemm_bt(
    const __hip_bfloat16* __restrict__ A, const __hip_bfloat16* __restrict__ Bt,
    const float* __restrict__ bias, float* __restrict__ outF,
    _Float16* __restrict__ Qb, _Float16* __restrict__ Kb,
    _Float16* __restrict__ VT) {
  constexpr int BM = (EPI == 0) ? 128 : 64;
  constexpr int BN = (EPI == 0) ? 96 : 64;
  constexpr int MT = BM / 32;  // 16-tiles per wave (m)
  constexpr int NT = BN / 32;  // 16-tiles per wave (n)
  __shared__ __align__(16) __hip_bfloat16 At[BM * 64];
  __shared__ __align__(16) __hip_bfloat16 Btl[BN * 64];
  const int tid = threadIdx.x;
  const int w = tid >> 6, l = tid & 63;
  const int quad = l >> 4, lane16 = l & 15;
  const int m0 = blockIdx.x * BM, n0 = blockIdx.y * BN;

  float4v acc[MT][NT];
#pragma unroll
  for (int i = 0; i < MT; i++)
#pragma unroll
    for (int j = 0; j < NT; j++) acc[i][j] = float4v{0.f, 0.f, 0.f, 0.f};

  const int srow = tid >> 3, sgr = tid & 7;
  const __hip_bfloat16* Asrc = A + (long long)(m0 + srow) * 768 + ((sgr ^ (srow & 7)) * 8);
  const __hip_bfloat16* Bsrc = Bt + (long long)(n0 + srow) * 768 + ((sgr ^ (srow & 7)) * 8);
  __hip_bfloat16* Adst = At + tid * 8;
  __hip_bfloat16* Bdst = Btl + tid * 8;

  const int wr = (w >> 1) * (BM / 2), wc = (w & 1) * (BN / 2);
  const int swz = lane16 & 7;

  for (int kt = 0; kt < 12; kt++) {
    const int k0 = kt * 64;
    __syncthreads();
#pragma unroll
    for (int c = 0; c < BM / 32; c++)
      async_copy16(Asrc + (long long)c * 32 * 768 + k0, Adst + c * 2048);
#pragma unroll
    for (int c = 0; c < BN / 32; c++)
      async_copy16(Bsrc + (long long)c * 32 * 768 + k0, Bdst + c * 2048);
    __syncthreads();
#pragma unroll
    for (int h = 0; h < 2; h++) {
      short8 af[MT], bf[NT];
#pragma unroll
      for (int t = 0; t < MT; t++)
        af[t] = *(const short8*)(At + (wr + t * 16 + lane16) * 64 +
                                 (((h * 4 + quad) ^ swz) * 8));
#pragma unroll
      for (int t = 0; t < NT; t++)
        bf[t] = *(const short8*)(Btl + (wc + t * 16 + lane16) * 64 +
                                 (((h * 4 + quad) ^ swz) * 8));
#pragma unroll
      for (int i = 0; i < MT; i++)
#pragma unroll
        for (int j = 0; j < NT; j++)
          acc[i][j] = __builtin_amdgcn_mfma_f32_16x16x32_bf16(af[i], bf[j], acc[i][j], 0, 0, 0);
    }
  }

  // epilogue: C/D layout col=lane16, row=quad*4+reg
#pragma unroll
  for (int i = 0; i < MT; i++) {
    const int mbase = m0 + wr + i * 16 + quad * 4;
#pragma unroll
    for (int j = 0; j < NT; j++) {
      const int n = n0 + wc + j * 16 + lane16;
      const float bv = bias[n];
      if (EPI == 0) {
        const int which = n / 768;  // uniform across the 16-lane tile
        const int rr = n - which * 768;
        const int hh = rr >> 6, dh = rr & 63;
        const float scale = (which == 0) ? LOG2E_8 : 1.0f;
#pragma unroll
        for (int r = 0; r < 4; r++) {
          const int mm = mbase + r;
          const int b = mm >> 11, s = mm & 2047;
          _Float16 val = (_Float16)((acc[i][j][r] + bv) * scale);
          if (which == 0)
            Qb[((long long)(b * 12 + hh) * 2048 + s) * 64 + dh] = val;
          else if (which == 1)
            Kb[((long long)(b * 12 + hh) * 2048 + s) * 64 + dh] = val;
          else
            VT[((long long)(b * 12 + hh) * 64 + dh) * 2048 + s] = val;
        }
      } else {
#pragma unroll
        for (int r = 0; r < 4; r++)
          outF[(long long)(mbase + r) * 768 + n] = acc[i][j][r] + bv;
      }
    }
  }
}

// ---- attention, f16, S^T form, key-split x2, 64-key tiles ------------------
// grid (S/64, B*H, 2). 4 waves; wave = 16 q-rows over 1024 keys (16 iters).
// Writes f32 partial O^T and partial denominator.
__global__ __launch_bounds__(256, 6) void k_attn(
    const _Float16* __restrict__ Qb, const _Float16* __restrict__ Kb,
    const _Float16* __restrict__ VT, float* __restrict__ Op,
    float* __restrict__ Sm) {
  __shared__ __align__(16) _Float16 Kl[64 * 64];  // [key][dh], slot g^(r&7)
  __shared__ __align__(16) _Float16 Vl[64 * 64];  // [dh][key], slot g^(r&7)
  const int tid = threadIdx.x, w = tid >> 6, l = tid & 63;
  const int quad = l >> 4, lane16 = l & 15;
  const int bh = blockIdx.y, z = blockIdx.z;
  const int q0 = blockIdx.x * 64 + w * 16;
  const _Float16* Qp = Qb + (long long)bh * 2048 * 64;
  const _Float16* Kp = Kb + (long long)bh * 2048 * 64;
  const _Float16* Vp = VT + (long long)bh * 64 * 2048;

  // Q as B-frag of S^T: B[n=q=lane16][k=dh=quad*8+j], two k-halves
  half8 qf[2];
#pragma unroll
  for (int hh = 0; hh < 2; hh++)
    qf[hh] = *(const half8*)(Qp + (q0 + lane16) * 64 + hh * 32 + quad * 8);

  float4v o_acc[4];  // O^T[dh=dt*16+quad*4+r][q=lane16]
#pragma unroll
  for (int t = 0; t < 4; t++) o_acc[t] = float4v{0.f, 0.f, 0.f, 0.f};
  float4v sum_acc = float4v{0.f, 0.f, 0.f, 0.f};  // denom via mfma(ones,P)
  const half4 ones = {(_Float16)1.f, (_Float16)1.f, (_Float16)1.f, (_Float16)1.f};

  // staging: rows of 8 granules; thread t -> row t>>3 (+32 on 2nd call),
  // source granule (t&7)^(row&7), dest slot t&7.
  const int srow = tid >> 3, sgr = (tid & 7) ^ ((tid >> 3) & 7);
  const _Float16* Ksrc = Kp + (long long)(z * 1024 + srow) * 64 + sgr * 8;
  const _Float16* Vsrc = Vp + (long long)srow * 2048 + z * 1024 + sgr * 8;
  _Float16* Kdst = Kl + tid * 8;
  _Float16* Vdst = Vl + tid * 8;
  const int swz = lane16 & 7;

  for (int kt = 0; kt < 16; kt++) {
    __syncthreads();
#pragma unroll
    for (int c = 0; c < 2; c++) {
      async_copy16(Ksrc + kt * 4096 + (long long)c * 32 * 64, Kdst + c * 2048);
      async_copy16(Vsrc + kt * 64 + (long long)c * 32 * 2048, Vdst + c * 2048);
    }
    __syncthreads();

    // S^T = K Q^T : A = K-frag [m=key][k=dh]  (Q carries log2e/8)
    float4v s[4];
#pragma unroll
    for (int kb = 0; kb < 4; kb++) {
      const _Float16* kr = Kl + (kb * 16 + lane16) * 64;
      half8 kf0 = *(const half8*)(kr + ((quad ^ swz) * 8));
      half8 kf1 = *(const half8*)(kr + (((4 + quad) ^ swz) * 8));
      float4v zz = float4v{0.f, 0.f, 0.f, 0.f};
      zz = __builtin_amdgcn_mfma_f32_16x16x32_f16(kf0, qf[0], zz, 0, 0, 0);
      s[kb] = __builtin_amdgcn_mfma_f32_16x16x32_f16(kf1, qf[1], zz, 0, 0, 0);
    }
    // p = exp2(s'); P^T packed (pk cvt) as K=16 B-frags (k = quad*4 + r)
    half4 pf[4];
#pragma unroll
    for (int kb = 0; kb < 4; kb++) {
      float p0 = fast_exp2(s[kb][0]);
      float p1 = fast_exp2(s[kb][1]);
      float p2 = fast_exp2(s[kb][2]);
      float p3 = fast_exp2(s[kb][3]);
      auto lo = __builtin_amdgcn_cvt_pkrtz(p0, p1);
      auto hi = __builtin_amdgcn_cvt_pkrtz(p2, p3);
      pf[kb] = half4{static_cast<_Float16>(lo[0]), static_cast<_Float16>(lo[1]),
                     static_cast<_Float16>(hi[0]), static_cast<_Float16>(hi[1])};
    }
#pragma unroll
    for (int kb = 0; kb < 4; kb++)
      sum_acc = __builtin_amdgcn_mfma_f32_16x16x16f16(ones, pf[kb], sum_acc, 0, 0, 0);
    // O^T += V^T P^T : A = V-frag [m=dh][k=key]
#pragma unroll
    for (int dt = 0; dt < 4; dt++) {
      const _Float16* vr = Vl + (dt * 16 + lane16) * 64;
#pragma unroll
      for (int kb = 0; kb < 4; kb++) {
        const int g16 = kb * 2 + (quad >> 1);
        half4 vf = *(const half4*)(vr + ((g16 ^ swz) * 8) + (quad & 1) * 4);
        o_acc[dt] = __builtin_amdgcn_mfma_f32_16x16x16f16(vf, pf[kb], o_acc[dt], 0, 0, 0);
      }
    }
  }
  // write f32 partials; every lane holds the partial denom for q=lane16
  const int b = bh / 12, hd = bh - (bh / 12) * 12;
  float* op = Op + (long long)z * 4096 * 768 +
              ((long long)b * 2048 + q0 + lane16) * 768 + hd * 64 + quad * 4;
#pragma unroll
  for (int dt = 0; dt < 4; dt++) *(float4v*)(op + dt * 16) = o_acc[dt];
  if (quad == 0)
    Sm[(long long)z * 24 * 2048 + bh * 2048 + q0 + lane16] = sum_acc[0];
}

// ---- combine: ctx_bf16 = (O0 + O1) / (s0 + s1) -----------------------------
__global__ __launch_bounds__(256) void k_comb(const float* __restrict__ Op,
                                              const float* __restrict__ Sm,
                                              unsigned short* __restrict__ ctx) {
  int i = blockIdx.x * 256 + threadIdx.x;  // float4 index, 786432 total
  const int e = i << 2;
  const int row = e / 768;                 // 0..4095
  const int col = e - row * 768;
  const int bh = (row >> 11) * 12 + (col >> 6);
  const int s_idx = row & 2047;
  const float s0 = Sm[bh * 2048 + s_idx];
  const float s1 = Sm[24 * 2048 + bh * 2048 + s_idx];
  const float inv = 1.0f / (s0 + s1);
  float4v a = ((const float4v*)Op)[i];
  float4v b = ((const float4v*)(Op + 4096ull * 768))[i];
  ushort4v o;
#pragma unroll
  for (int r = 0; r < 4; r++) o[r] = f2bf((a[r] + b[r]) * inv);
  ((ushort4v*)ctx)[i] = o;
}

extern "C" void kernel_launch(void* const* d_in, const int* in_sizes, int n_in,
                              void* d_out, int out_size, void* d_ws, size_t ws_size,
                              hipStream_t stream) {
  const float* x = (const float*)d_in[0];
  // d_in[1] attention_mask: masks scaled by +1e-9 -> no-op, dropped
  const float* w_qkv = (const float*)d_in[2];
  const float* b_qkv = (const float*)d_in[3];
  const float* w_proj = (const float*)d_in[4];
  const float* b_proj = (const float*)d_in[5];
  float* out = (float*)d_out;

  char* ws = (char*)d_ws;
  size_t off = 0;
  auto alloc = [&](size_t bytes) {
    void* p = ws + off;
    off += (bytes + 255) & ~(size_t)255;
    return p;
  };
  __hip_bfloat16* Xb = (__hip_bfloat16*)alloc(4096ull * 768 * 2);      // 6.3 MB
  __hip_bfloat16* WqkvT = (__hip_bfloat16*)alloc(2304ull * 768 * 2);   // 3.5 MB
  __hip_bfloat16* WprojT = (__hip_bfloat16*)alloc(768ull * 768 * 2);   // 1.2 MB
  _Float16* Qb = (_Float16*)alloc(3145728ull * 2);                     // 6.3 MB
  _Float16* Kb = (_Float16*)alloc(3145728ull * 2);                     // 6.3 MB
  _Float16* VT = (_Float16*)alloc(3145728ull * 2);                     // 6.3 MB
  __hip_bfloat16* ctx = (__hip_bfloat16*)alloc(4096ull * 768 * 2);     // 6.3 MB
  float* Op = (float*)alloc(2ull * 4096 * 768 * 4);                    // 25.2 MB
  float* Sm = (float*)alloc(2ull * 24 * 2048 * 4);                     // 0.4 MB

  k_prep<<<5376, 256, 0, stream>>>(x, (unsigned short*)Xb, w_qkv, WqkvT,
                                   w_proj, WprojT);
  k_gemm_bt<0><<<dim3(32, 24), 256, 0, stream>>>(Xb, WqkvT, b_qkv, nullptr,
                                                 Qb, Kb, VT);
  k_attn<<<dim3(32, 24, 2), 256, 0, stream>>>(Qb, Kb, VT, Op, Sm);
  k_comb<<<3072, 256, 0, stream>>>(Op, Sm, (unsigned short*)ctx);
  k_gemm_bt<1><<<dim3(64, 12), 256, 0, stream>>>(ctx, WprojT, b_proj, out,
                                                 nullptr, nullptr, nullptr);
}

// Round 7
// 156.992 us; speedup vs baseline: 1.0142x; 1.0142x over previous
//
#include <hip/hip_runtime.h>
#include <hip/hip_bf16.h>

// ---------------------------------------------------------------------------
// MultiHeadAttention forward on MI355X (gfx950). B=2,S=2048,D=768,H=12,Dh=64.
// Masks scale by +1e-9 (numeric no-op) -> full non-causal softmax; dropped.
//
// Round 7: attention LDS-pipe attack. R6 counters: MFMA 38 + VALU 28, 34%
// idle at 41% occupancy -> per-MFMA LDS reads are the serializer (b128 ~12cyc
// feeds one K=32 MFMA ~4.6cyc). Fix: 32 q-rows per wave (2 register-resident
// Q/P frags) so every K/V LDS read feeds 2 MFMAs. Block=128q, 64-key tiles,
// key-split z=2, grid (16,24,2)=768=3/CU, __launch_bounds__(256,3).
// ---------------------------------------------------------------------------

typedef __attribute__((ext_vector_type(8))) short short8;
typedef __attribute__((ext_vector_type(4))) float float4v;
typedef __attribute__((ext_vector_type(8))) _Float16 half8;
typedef __attribute__((ext_vector_type(4))) _Float16 half4;
typedef __attribute__((ext_vector_type(4))) unsigned short ushort4v;

__device__ __forceinline__ void async_copy16(const void* g, void* l) {
  __builtin_amdgcn_global_load_lds(
      (const __attribute__((address_space(1))) void*)g,
      (__attribute__((address_space(3))) void*)l, 16, 0, 0);
}

__device__ __forceinline__ float fast_exp2(float x) {
#if __has_builtin(__builtin_amdgcn_exp2f)
  return __builtin_amdgcn_exp2f(x);
#else
  return exp2f(x);
#endif
}

__device__ __forceinline__ unsigned short f2bf(float v) {
  __hip_bfloat16 h = __float2bfloat16(v);
  unsigned short u;
  __builtin_memcpy(&u, &h, 2);
  return u;
}

#define LOG2E_8 0.18033688011112042f  // log2(e)/8, folded into Q

// ---- fused prep: x f32->bf16 cast; w_qkv, w_proj transpose->bf16 -----------
__global__ __launch_bounds__(256) void k_prep(
    const float* __restrict__ x, unsigned short* __restrict__ xb,
    const float* __restrict__ wqkv, __hip_bfloat16* __restrict__ wqkvT,
    const float* __restrict__ wproj, __hip_bfloat16* __restrict__ wprojT) {
  __shared__ float tile[32][33];
  const int bid = blockIdx.x, tid = threadIdx.x;
  if (bid < 3072) {  // cast: 4096*768 floats, 4/thread
    int i = bid * 256 + tid;
    float4v v = ((const float4v*)x)[i];
    ushort4v o;
#pragma unroll
    for (int r = 0; r < 4; r++) o[r] = f2bf(v[r]);
    ((ushort4v*)xb)[i] = o;
    return;
  }
  const float* w;
  __hip_bfloat16* wt;
  int N, bx, by;
  if (bid < 4800) {
    int t = bid - 3072; w = wqkv; wt = wqkvT; N = 2304; bx = t % 72; by = t / 72;
  } else {
    int t = bid - 4800; w = wproj; wt = wprojT; N = 768; bx = t % 24; by = t / 24;
  }
  const int n0 = bx * 32, k0 = by * 32;
  const int r = tid >> 5, c = tid & 31;
#pragma unroll
  for (int rr = 0; rr < 32; rr += 8)
    tile[rr + r][c] = w[(long long)(k0 + rr + r) * N + n0 + c];
  __syncthreads();
#pragma unroll
  for (int rr = 0; rr < 32; rr += 8)
    wt[(long long)(n0 + rr + r) * 768 + k0 + c] = __float2bfloat16(tile[c][rr + r]);
}

// ---- bf16 GEMM, BK=64, K=768 (12 iters), conflict-free XOR swizzle ---------
// EPI==0: 128x96 tile; scatter Q(prescaled),K->[B,H,S,64] f16, V->VT (+bias).
// EPI==1: 64x64 tile; out f32 [M][768] = acc + bias.
template <int EPI>
__global__ __launch_bounds__(256) void k_gemm_bt(
    const __hip_bfloat16* __restrict__ A, const __hip_bfloat16* __restrict__ Bt,
    const float* __restrict__ bias, float* __restrict__ outF,
    _Float16* __restrict__ Qb, _Float16* __restrict__ Kb,
    _Float16* __restrict__ VT) {
  constexpr int BM = (EPI == 0) ? 128 : 64;
  constexpr int BN = (EPI == 0) ? 96 : 64;
  constexpr int MT = BM / 32;  // 16-tiles per wave (m)
  constexpr int NT = BN / 32;  // 16-tiles per wave (n)
  __shared__ __align__(16) __hip_bfloat16 At[BM * 64];
  __shared__ __align__(16) __hip_bfloat16 Btl[BN * 64];
  const int tid = threadIdx.x;
  const int w = tid >> 6, l = tid & 63;
  const int quad = l >> 4, lane16 = l & 15;
  const int m0 = blockIdx.x * BM, n0 = blockIdx.y * BN;

  float4v acc[MT][NT];
#pragma unroll
  for (int i = 0; i < MT; i++)
#pragma unroll
    for (int j = 0; j < NT; j++) acc[i][j] = float4v{0.f, 0.f, 0.f, 0.f};

  const int srow = tid >> 3, sgr = tid & 7;
  const __hip_bfloat16* Asrc = A + (long long)(m0 + srow) * 768 + ((sgr ^ (srow & 7)) * 8);
  const __hip_bfloat16* Bsrc = Bt + (long long)(n0 + srow) * 768 + ((sgr ^ (srow & 7)) * 8);
  __hip_bfloat16* Adst = At + tid * 8;
  __hip_bfloat16* Bdst = Btl + tid * 8;

  const int wr = (w >> 1) * (BM / 2), wc = (w & 1) * (BN / 2);
  const int swz = lane16 & 7;

  for (int kt = 0; kt < 12; kt++) {
    const int k0 = kt * 64;
    __syncthreads();
#pragma unroll
    for (int c = 0; c < BM / 32; c++)
      async_copy16(Asrc + (long long)c * 32 * 768 + k0, Adst + c * 2048);
#pragma unroll
    for (int c = 0; c < BN / 32; c++)
      async_copy16(Bsrc + (long long)c * 32 * 768 + k0, Bdst + c * 2048);
    __syncthreads();
#pragma unroll
    for (int h = 0; h < 2; h++) {
      short8 af[MT], bf[NT];
#pragma unroll
      for (int t = 0; t < MT; t++)
        af[t] = *(const short8*)(At + (wr + t * 16 + lane16) * 64 +
                                 (((h * 4 + quad) ^ swz) * 8));
#pragma unroll
      for (int t = 0; t < NT; t++)
        bf[t] = *(const short8*)(Btl + (wc + t * 16 + lane16) * 64 +
                                 (((h * 4 + quad) ^ swz) * 8));
#pragma unroll
      for (int i = 0; i < MT; i++)
#pragma unroll
        for (int j = 0; j < NT; j++)
          acc[i][j] = __builtin_amdgcn_mfma_f32_16x16x32_bf16(af[i], bf[j], acc[i][j], 0, 0, 0);
    }
  }

  // epilogue: C/D layout col=lane16, row=quad*4+reg
#pragma unroll
  for (int i = 0; i < MT; i++) {
    const int mbase = m0 + wr + i * 16 + quad * 4;
#pragma unroll
    for (int j = 0; j < NT; j++) {
      const int n = n0 + wc + j * 16 + lane16;
      const float bv = bias[n];
      if (EPI == 0) {
        const int which = n / 768;  // uniform across the 16-lane tile
        const int rr = n - which * 768;
        const int hh = rr >> 6, dh = rr & 63;
        const float scale = (which == 0) ? LOG2E_8 : 1.0f;
#pragma unroll
        for (int r = 0; r < 4; r++) {
          const int mm = mbase + r;
          const int b = mm >> 11, s = mm & 2047;
          _Float16 val = (_Float16)((acc[i][j][r] + bv) * scale);
          if (which == 0)
            Qb[((long long)(b * 12 + hh) * 2048 + s) * 64 + dh] = val;
          else if (which == 1)
            Kb[((long long)(b * 12 + hh) * 2048 + s) * 64 + dh] = val;
          else
            VT[((long long)(b * 12 + hh) * 64 + dh) * 2048 + s] = val;
        }
      } else {
#pragma unroll
        for (int r = 0; r < 4; r++)
          outF[(long long)(mbase + r) * 768 + n] = acc[i][j][r] + bv;
      }
    }
  }
}

// ---- attention: 32 q/wave, f16, S^T form, key-split x2, 64-key tiles -------
// grid (S/128, B*H, 2). 4 waves x 32 q = 128 q-rows; 1024 keys each (16 it).
// Every K-frag (b128) and V-frag (b64) LDS read feeds TWO MFMAs (q-groups).
// Writes f32 partial O^T and partial denominator.
__global__ __launch_bounds__(256, 3) void k_attn(
    const _Float16* __restrict__ Qb, const _Float16* __restrict__ Kb,
    const _Float16* __restrict__ VT, float* __restrict__ Op,
    float* __restrict__ Sm) {
  __shared__ __align__(16) _Float16 Kl[64 * 64];  // [key][dh], slot g^(r&7)
  __shared__ __align__(16) _Float16 Vl[64 * 64];  // [dh][key], slot g^(r&7)
  const int tid = threadIdx.x, w = tid >> 6, l = tid & 63;
  const int quad = l >> 4, lane16 = l & 15;
  const int bh = blockIdx.y, z = blockIdx.z;
  const int q0w = blockIdx.x * 128 + w * 32;
  const _Float16* Qp = Qb + (long long)bh * 2048 * 64;
  const _Float16* Kp = Kb + (long long)bh * 2048 * 64;
  const _Float16* Vp = VT + (long long)bh * 64 * 2048;

  // Q as B-frags of S^T: B[n=q=lane16][k=dh=quad*8+j], 2 q-groups x 2 k-halves
  half8 qf[2][2];
#pragma unroll
  for (int g = 0; g < 2; g++)
#pragma unroll
    for (int hh = 0; hh < 2; hh++)
      qf[g][hh] = *(const half8*)(Qp + (q0w + g * 16 + lane16) * 64 + hh * 32 + quad * 8);

  float4v o_acc[2][4];  // O^T[dh=dt*16+quad*4+r][q(group g)=lane16]
#pragma unroll
  for (int g = 0; g < 2; g++)
#pragma unroll
    for (int t = 0; t < 4; t++) o_acc[g][t] = float4v{0.f, 0.f, 0.f, 0.f};
  float4v sum_acc[2] = {float4v{0.f, 0.f, 0.f, 0.f}, float4v{0.f, 0.f, 0.f, 0.f}};
  const half4 ones = {(_Float16)1.f, (_Float16)1.f, (_Float16)1.f, (_Float16)1.f};

  // staging: rows of 8 granules; thread t -> row t>>3 (+32 on 2nd call),
  // source granule (t&7)^(row&7), dest slot t&7.
  const int srow = tid >> 3, sgr = (tid & 7) ^ ((tid >> 3) & 7);
  const _Float16* Ksrc = Kp + (long long)(z * 1024 + srow) * 64 + sgr * 8;
  const _Float16* Vsrc = Vp + (long long)srow * 2048 + z * 1024 + sgr * 8;
  _Float16* Kdst = Kl + tid * 8;
  _Float16* Vdst = Vl + tid * 8;
  const int swz = lane16 & 7;

  for (int kt = 0; kt < 16; kt++) {
    __syncthreads();
#pragma unroll
    for (int c = 0; c < 2; c++) {
      async_copy16(Ksrc + kt * 4096 + (long long)c * 32 * 64, Kdst + c * 2048);
      async_copy16(Vsrc + kt * 64 + (long long)c * 32 * 2048, Vdst + c * 2048);
    }
    __syncthreads();

    // S^T = K Q^T : A = K-frag [m=key][k=dh]; each load feeds both q-groups
    float4v s[2][4];
#pragma unroll
    for (int kb = 0; kb < 4; kb++) {
      const _Float16* kr = Kl + (kb * 16 + lane16) * 64;
      half8 kf0 = *(const half8*)(kr + ((quad ^ swz) * 8));
      half8 kf1 = *(const half8*)(kr + (((4 + quad) ^ swz) * 8));
#pragma unroll
      for (int g = 0; g < 2; g++) {
        float4v zz = float4v{0.f, 0.f, 0.f, 0.f};
        zz = __builtin_amdgcn_mfma_f32_16x16x32_f16(kf0, qf[g][0], zz, 0, 0, 0);
        s[g][kb] = __builtin_amdgcn_mfma_f32_16x16x32_f16(kf1, qf[g][1], zz, 0, 0, 0);
      }
    }
    // p = exp2(s'); P^T packed (pk cvt) as K=16 B-frags (k = quad*4 + r)
    half4 pf[2][4];
#pragma unroll
    for (int g = 0; g < 2; g++)
#pragma unroll
      for (int kb = 0; kb < 4; kb++) {
        float p0 = fast_exp2(s[g][kb][0]);
        float p1 = fast_exp2(s[g][kb][1]);
        float p2 = fast_exp2(s[g][kb][2]);
        float p3 = fast_exp2(s[g][kb][3]);
        auto lo = __builtin_amdgcn_cvt_pkrtz(p0, p1);
        auto hi = __builtin_amdgcn_cvt_pkrtz(p2, p3);
        pf[g][kb] = half4{static_cast<_Float16>(lo[0]), static_cast<_Float16>(lo[1]),
                          static_cast<_Float16>(hi[0]), static_cast<_Float16>(hi[1])};
      }
#pragma unroll
    for (int g = 0; g < 2; g++)
#pragma unroll
      for (int kb = 0; kb < 4; kb++)
        sum_acc[g] = __builtin_amdgcn_mfma_f32_16x16x16f16(ones, pf[g][kb], sum_acc[g], 0, 0, 0);
    // O^T += V^T P^T : A = V-frag [m=dh][k=key]; each load feeds both groups
#pragma unroll
    for (int dt = 0; dt < 4; dt++) {
      const _Float16* vr = Vl + (dt * 16 + lane16) * 64;
#pragma unroll
      for (int kb = 0; kb < 4; kb++) {
        const int g16 = kb * 2 + (quad >> 1);
        half4 vf = *(const half4*)(vr + ((g16 ^ swz) * 8) + (quad & 1) * 4);
#pragma unroll
        for (int g = 0; g < 2; g++)
          o_acc[g][dt] = __builtin_amdgcn_mfma_f32_16x16x16f16(vf, pf[g][kb], o_acc[g][dt], 0, 0, 0);
      }
    }
  }
  // write f32 partials; every lane holds the partial denom for its q
  const int b = bh / 12, hd = bh - (bh / 12) * 12;
#pragma unroll
  for (int g = 0; g < 2; g++) {
    const int qrow = q0w + g * 16 + lane16;
    float* op = Op + (long long)z * 4096 * 768 +
                ((long long)b * 2048 + qrow) * 768 + hd * 64 + quad * 4;
#pragma unroll
    for (int dt = 0; dt < 4; dt++) *(float4v*)(op + dt * 16) = o_acc[g][dt];
    if (quad == 0)
      Sm[(long long)z * 24 * 2048 + bh * 2048 + qrow] = sum_acc[g][0];
  }
}

// ---- combine: ctx_bf16 = (O0 + O1) / (s0 + s1) -----------------------------
__global__ __launch_bounds__(256) void k_comb(const float* __restrict__ Op,
                                              const float* __restrict__ Sm,
                                              unsigned short* __restrict__ ctx) {
  int i = blockIdx.x * 256 + threadIdx.x;  // float4 index, 786432 total
  const int e = i << 2;
  const int row = e / 768;                 // 0..4095
  const int col = e - row * 768;
  const int bh = (row >> 11) * 12 + (col >> 6);
  const int s_idx = row & 2047;
  const float s0 = Sm[bh * 2048 + s_idx];
  const float s1 = Sm[24 * 2048 + bh * 2048 + s_idx];
  const float inv = 1.0f / (s0 + s1);
  float4v a = ((const float4v*)Op)[i];
  float4v b = ((const float4v*)(Op + 4096ull * 768))[i];
  ushort4v o;
#pragma unroll
  for (int r = 0; r < 4; r++) o[r] = f2bf((a[r] + b[r]) * inv);
  ((ushort4v*)ctx)[i] = o;
}

extern "C" void kernel_launch(void* const* d_in, const int* in_sizes, int n_in,
                              void* d_out, int out_size, void* d_ws, size_t ws_size,
                              hipStream_t stream) {
  const float* x = (const float*)d_in[0];
  // d_in[1] attention_mask: masks scaled by +1e-9 -> no-op, dropped
  const float* w_qkv = (const float*)d_in[2];
  const float* b_qkv = (const float*)d_in[3];
  const float* w_proj = (const float*)d_in[4];
  const float* b_proj = (const float*)d_in[5];
  float* out = (float*)d_out;

  char* ws = (char*)d_ws;
  size_t off = 0;
  auto alloc = [&](size_t bytes) {
    void* p = ws + off;
    off += (bytes + 255) & ~(size_t)255;
    return p;
  };
  __hip_bfloat16* Xb = (__hip_bfloat16*)alloc(4096ull * 768 * 2);      // 6.3 MB
  __hip_bfloat16* WqkvT = (__hip_bfloat16*)alloc(2304ull * 768 * 2);   // 3.5 MB
  __hip_bfloat16* WprojT = (__hip_bfloat16*)alloc(768ull * 768 * 2);   // 1.2 MB
  _Float16* Qb = (_Float16*)alloc(3145728ull * 2);                     // 6.3 MB
  _Float16* Kb = (_Float16*)alloc(3145728ull * 2);                     // 6.3 MB
  _Float16* VT = (_Float16*)alloc(3145728ull * 2);                     // 6.3 MB
  __hip_bfloat16* ctx = (__hip_bfloat16*)alloc(4096ull * 768 * 2);     // 6.3 MB
  float* Op = (float*)alloc(2ull * 4096 * 768 * 4);                    // 25.2 MB
  float* Sm = (float*)alloc(2ull * 24 * 2048 * 4);                     // 0.4 MB

  k_prep<<<5376, 256, 0, stream>>>(x, (unsigned short*)Xb, w_qkv, WqkvT,
                                   w_proj, WprojT);
  k_gemm_bt<0><<<dim3(32, 24), 256, 0, stream>>>(Xb, WqkvT, b_qkv, nullptr,
                                                 Qb, Kb, VT);
  k_attn<<<dim3(16, 24, 2), 256, 0, stream>>>(Qb, Kb, VT, Op, Sm);
  k_comb<<<3072, 256, 0, stream>>>(Op, Sm, (unsigned short*)ctx);
  k_gemm_bt<1><<<dim3(64, 12), 256, 0, stream>>>(ctx, WprojT, b_proj, out,
                                                 nullptr, nullptr, nullptr);
}

// Round 8
// 154.574 us; speedup vs baseline: 1.0301x; 1.0156x over previous
//
#include <hip/hip_runtime.h>
#include <hip/hip_bf16.h>

// ---------------------------------------------------------------------------
// MultiHeadAttention forward on MI355X (gfx950). B=2,S=2048,D=768,H=12,Dh=64.
// Masks scale by +1e-9 (numeric no-op) -> full non-causal softmax; dropped.
//
// Round 8: attention barrier-drain attack. R7 counters: MFMA 40 + VALU 27,
// 33% idle; per-iter pipes are balanced (MFMA~166 / VALU~200 / LDS~192 cyc)
// so the idle is the staging drain (loads issued immediately before the
// barrier that drains them). Fix: double-buffered K/V staging -- prefetch
// tile kt+1 after publishing tile kt, drain lands after ~500cyc of compute.
// Also: bf16 partial O (attn write 25->12.5 MB, comb 57->19 MB).
// ---------------------------------------------------------------------------

typedef __attribute__((ext_vector_type(8))) short short8;
typedef __attribute__((ext_vector_type(4))) float float4v;
typedef __attribute__((ext_vector_type(8))) _Float16 half8;
typedef __attribute__((ext_vector_type(4))) _Float16 half4;
typedef __attribute__((ext_vector_type(4))) unsigned short ushort4v;

__device__ __forceinline__ void async_copy16(const void* g, void* l) {
  __builtin_amdgcn_global_load_lds(
      (const __attribute__((address_space(1))) void*)g,
      (__attribute__((address_space(3))) void*)l, 16, 0, 0);
}

__device__ __forceinline__ float fast_exp2(float x) {
#if __has_builtin(__builtin_amdgcn_exp2f)
  return __builtin_amdgcn_exp2f(x);
#else
  return exp2f(x);
#endif
}

__device__ __forceinline__ unsigned short f2bf(float v) {
  __hip_bfloat16 h = __float2bfloat16(v);
  unsigned short u;
  __builtin_memcpy(&u, &h, 2);
  return u;
}

__device__ __forceinline__ float bf2f(unsigned short u) {
  unsigned int x = ((unsigned int)u) << 16;
  float f;
  __builtin_memcpy(&f, &x, 4);
  return f;
}

#define LOG2E_8 0.18033688011112042f  // log2(e)/8, folded into Q

// ---- fused prep: x f32->bf16 cast; w_qkv, w_proj transpose->bf16 -----------
__global__ __launch_bounds__(256) void k_prep(
    const float* __restrict__ x, unsigned short* __restrict__ xb,
    const float* __restrict__ wqkv, __hip_bfloat16* __restrict__ wqkvT,
    const float* __restrict__ wproj, __hip_bfloat16* __restrict__ wprojT) {
  __shared__ float tile[32][33];
  const int bid = blockIdx.x, tid = threadIdx.x;
  if (bid < 3072) {  // cast: 4096*768 floats, 4/thread
    int i = bid * 256 + tid;
    float4v v = ((const float4v*)x)[i];
    ushort4v o;
#pragma unroll
    for (int r = 0; r < 4; r++) o[r] = f2bf(v[r]);
    ((ushort4v*)xb)[i] = o;
    return;
  }
  const float* w;
  __hip_bfloat16* wt;
  int N, bx, by;
  if (bid < 4800) {
    int t = bid - 3072; w = wqkv; wt = wqkvT; N = 2304; bx = t % 72; by = t / 72;
  } else {
    int t = bid - 4800; w = wproj; wt = wprojT; N = 768; bx = t % 24; by = t / 24;
  }
  const int n0 = bx * 32, k0 = by * 32;
  const int r = tid >> 5, c = tid & 31;
#pragma unroll
  for (int rr = 0; rr < 32; rr += 8)
    tile[rr + r][c] = w[(long long)(k0 + rr + r) * N + n0 + c];
  __syncthreads();
#pragma unroll
  for (int rr = 0; rr < 32; rr += 8)
    wt[(long long)(n0 + rr + r) * 768 + k0 + c] = __float2bfloat16(tile[c][rr + r]);
}

// ---- bf16 GEMM, BK=64, K=768 (12 iters), conflict-free XOR swizzle ---------
// EPI==0: 128x96 tile; scatter Q(prescaled),K->[B,H,S,64] f16, V->VT (+bias).
// EPI==1: 64x64 tile; out f32 [M][768] = acc + bias.
template <int EPI>
__global__ __launch_bounds__(256) void k_gemm_bt(
    const __hip_bfloat16* __restrict__ A, const __hip_bfloat16* __restrict__ Bt,
    const float* __restrict__ bias, float* __restrict__ outF,
    _Float16* __restrict__ Qb, _Float16* __restrict__ Kb,
    _Float16* __restrict__ VT) {
  constexpr int BM = (EPI == 0) ? 128 : 64;
  constexpr int BN = (EPI == 0) ? 96 : 64;
  constexpr int MT = BM / 32;  // 16-tiles per wave (m)
  constexpr int NT = BN / 32;  // 16-tiles per wave (n)
  __shared__ __align__(16) __hip_bfloat16 At[BM * 64];
  __shared__ __align__(16) __hip_bfloat16 Btl[BN * 64];
  const int tid = threadIdx.x;
  const int w = tid >> 6, l = tid & 63;
  const int quad = l >> 4, lane16 = l & 15;
  const int m0 = blockIdx.x * BM, n0 = blockIdx.y * BN;

  float4v acc[MT][NT];
#pragma unroll
  for (int i = 0; i < MT; i++)
#pragma unroll
    for (int j = 0; j < NT; j++) acc[i][j] = float4v{0.f, 0.f, 0.f, 0.f};

  const int srow = tid >> 3, sgr = tid & 7;
  const __hip_bfloat16* Asrc = A + (long long)(m0 + srow) * 768 + ((sgr ^ (srow & 7)) * 8);
  const __hip_bfloat16* Bsrc = Bt + (long long)(n0 + srow) * 768 + ((sgr ^ (srow & 7)) * 8);
  __hip_bfloat16* Adst = At + tid * 8;
  __hip_bfloat16* Bdst = Btl + tid * 8;

  const int wr = (w >> 1) * (BM / 2), wc = (w & 1) * (BN / 2);
  const int swz = lane16 & 7;

  for (int kt = 0; kt < 12; kt++) {
    const int k0 = kt * 64;
    __syncthreads();
#pragma unroll
    for (int c = 0; c < BM / 32; c++)
      async_copy16(Asrc + (long long)c * 32 * 768 + k0, Adst + c * 2048);
#pragma unroll
    for (int c = 0; c < BN / 32; c++)
      async_copy16(Bsrc + (long long)c * 32 * 768 + k0, Bdst + c * 2048);
    __syncthreads();
#pragma unroll
    for (int h = 0; h < 2; h++) {
      short8 af[MT], bf[NT];
#pragma unroll
      for (int t = 0; t < MT; t++)
        af[t] = *(const short8*)(At + (wr + t * 16 + lane16) * 64 +
                                 (((h * 4 + quad) ^ swz) * 8));
#pragma unroll
      for (int t = 0; t < NT; t++)
        bf[t] = *(const short8*)(Btl + (wc + t * 16 + lane16) * 64 +
                                 (((h * 4 + quad) ^ swz) * 8));
#pragma unroll
      for (int i = 0; i < MT; i++)
#pragma unroll
        for (int j = 0; j < NT; j++)
          acc[i][j] = __builtin_amdgcn_mfma_f32_16x16x32_bf16(af[i], bf[j], acc[i][j], 0, 0, 0);
    }
  }

  // epilogue: C/D layout col=lane16, row=quad*4+reg
#pragma unroll
  for (int i = 0; i < MT; i++) {
    const int mbase = m0 + wr + i * 16 + quad * 4;
#pragma unroll
    for (int j = 0; j < NT; j++) {
      const int n = n0 + wc + j * 16 + lane16;
      const float bv = bias[n];
      if (EPI == 0) {
        const int which = n / 768;  // uniform across the 16-lane tile
        const int rr = n - which * 768;
        const int hh = rr >> 6, dh = rr & 63;
        const float scale = (which == 0) ? LOG2E_8 : 1.0f;
#pragma unroll
        for (int r = 0; r < 4; r++) {
          const int mm = mbase + r;
          const int b = mm >> 11, s = mm & 2047;
          _Float16 val = (_Float16)((acc[i][j][r] + bv) * scale);
          if (which == 0)
            Qb[((long long)(b * 12 + hh) * 2048 + s) * 64 + dh] = val;
          else if (which == 1)
            Kb[((long long)(b * 12 + hh) * 2048 + s) * 64 + dh] = val;
          else
            VT[((long long)(b * 12 + hh) * 64 + dh) * 2048 + s] = val;
        }
      } else {
#pragma unroll
        for (int r = 0; r < 4; r++)
          outF[(long long)(mbase + r) * 768 + n] = acc[i][j][r] + bv;
      }
    }
  }
}

// ---- attention: 32 q/wave, f16, S^T form, key-split x2, dbuf 64-key tiles --
// grid (S/128, B*H, 2). 4 waves x 32 q = 128 q-rows; 1024 keys each (16 it).
// Double-buffered staging: prefetch kt+1 issued right after the barrier that
// publishes kt, drained one full compute-phase later. bf16 partial output.
__global__ __launch_bounds__(256, 3) void k_attn(
    const _Float16* __restrict__ Qb, const _Float16* __restrict__ Kb,
    const _Float16* __restrict__ VT, unsigned short* __restrict__ Op,
    float* __restrict__ Sm) {
  __shared__ __align__(16) _Float16 Kl[2][64 * 64];  // [key][dh], slot g^(r&7)
  __shared__ __align__(16) _Float16 Vl[2][64 * 64];  // [dh][key], slot g^(r&7)
  const int tid = threadIdx.x, w = tid >> 6, l = tid & 63;
  const int quad = l >> 4, lane16 = l & 15;
  const int bh = blockIdx.y, z = blockIdx.z;
  const int q0w = blockIdx.x * 128 + w * 32;
  const _Float16* Qp = Qb + (long long)bh * 2048 * 64;
  const _Float16* Kp = Kb + (long long)bh * 2048 * 64;
  const _Float16* Vp = VT + (long long)bh * 64 * 2048;

  // Q as B-frags of S^T: B[n=q=lane16][k=dh=quad*8+j], 2 q-groups x 2 k-halves
  half8 qf[2][2];
#pragma unroll
  for (int g = 0; g < 2; g++)
#pragma unroll
    for (int hh = 0; hh < 2; hh++)
      qf[g][hh] = *(const half8*)(Qp + (q0w + g * 16 + lane16) * 64 + hh * 32 + quad * 8);

  float4v o_acc[2][4];  // O^T[dh=dt*16+quad*4+r][q(group g)=lane16]
#pragma unroll
  for (int g = 0; g < 2; g++)
#pragma unroll
    for (int t = 0; t < 4; t++) o_acc[g][t] = float4v{0.f, 0.f, 0.f, 0.f};
  float4v sum_acc[2] = {float4v{0.f, 0.f, 0.f, 0.f}, float4v{0.f, 0.f, 0.f, 0.f}};
  const half4 ones = {(_Float16)1.f, (_Float16)1.f, (_Float16)1.f, (_Float16)1.f};

  // staging: rows of 8 granules; thread t -> row t>>3 (+32 on 2nd call),
  // source granule (t&7)^(row&7), dest slot t&7.
  const int srow = tid >> 3, sgr = (tid & 7) ^ ((tid >> 3) & 7);
  const _Float16* Ksrc = Kp + (long long)(z * 1024 + srow) * 64 + sgr * 8;
  const _Float16* Vsrc = Vp + (long long)srow * 2048 + z * 1024 + sgr * 8;
  const int swz = lane16 & 7;

  auto stage = [&](int kt, int buf) {
    _Float16* Kdst = Kl[buf] + tid * 8;
    _Float16* Vdst = Vl[buf] + tid * 8;
#pragma unroll
    for (int c = 0; c < 2; c++) {
      async_copy16(Ksrc + kt * 4096 + (long long)c * 32 * 64, Kdst + c * 2048);
      async_copy16(Vsrc + kt * 64 + (long long)c * 32 * 2048, Vdst + c * 2048);
    }
  };

  stage(0, 0);  // prologue prefetch

  for (int kt = 0; kt < 16; kt++) {
    const int buf = kt & 1;
    __syncthreads();  // drains the prefetch issued one compute-phase ago
    if (kt < 15) stage(kt + 1, buf ^ 1);

    // S^T = K Q^T : A = K-frag [m=key][k=dh]; each load feeds both q-groups
    float4v s[2][4];
#pragma unroll
    for (int kb = 0; kb < 4; kb++) {
      const _Float16* kr = Kl[buf] + (kb * 16 + lane16) * 64;
      half8 kf0 = *(const half8*)(kr + ((quad ^ swz) * 8));
      half8 kf1 = *(const half8*)(kr + (((4 + quad) ^ swz) * 8));
#pragma unroll
      for (int g = 0; g < 2; g++) {
        float4v zz = float4v{0.f, 0.f, 0.f, 0.f};
        zz = __builtin_amdgcn_mfma_f32_16x16x32_f16(kf0, qf[g][0], zz, 0, 0, 0);
        s[g][kb] = __builtin_amdgcn_mfma_f32_16x16x32_f16(kf1, qf[g][1], zz, 0, 0, 0);
      }
    }
    // p = exp2(s'); P^T packed (pk cvt) as K=16 B-frags (k = quad*4 + r)
    half4 pf[2][4];
#pragma unroll
    for (int g = 0; g < 2; g++)
#pragma unroll
      for (int kb = 0; kb < 4; kb++) {
        float p0 = fast_exp2(s[g][kb][0]);
        float p1 = fast_exp2(s[g][kb][1]);
        float p2 = fast_exp2(s[g][kb][2]);
        float p3 = fast_exp2(s[g][kb][3]);
        auto lo = __builtin_amdgcn_cvt_pkrtz(p0, p1);
        auto hi = __builtin_amdgcn_cvt_pkrtz(p2, p3);
        pf[g][kb] = half4{static_cast<_Float16>(lo[0]), static_cast<_Float16>(lo[1]),
                          static_cast<_Float16>(hi[0]), static_cast<_Float16>(hi[1])};
      }
#pragma unroll
    for (int g = 0; g < 2; g++)
#pragma unroll
      for (int kb = 0; kb < 4; kb++)
        sum_acc[g] = __builtin_amdgcn_mfma_f32_16x16x16f16(ones, pf[g][kb], sum_acc[g], 0, 0, 0);
    // O^T += V^T P^T : A = V-frag [m=dh][k=key]; each load feeds both groups
#pragma unroll
    for (int dt = 0; dt < 4; dt++) {
      const _Float16* vr = Vl[buf] + (dt * 16 + lane16) * 64;
#pragma unroll
      for (int kb = 0; kb < 4; kb++) {
        const int g16 = kb * 2 + (quad >> 1);
        half4 vf = *(const half4*)(vr + ((g16 ^ swz) * 8) + (quad & 1) * 4);
#pragma unroll
        for (int g = 0; g < 2; g++)
          o_acc[g][dt] = __builtin_amdgcn_mfma_f32_16x16x16f16(vf, pf[g][kb], o_acc[g][dt], 0, 0, 0);
      }
    }
  }
  // write bf16 partials; every lane holds the partial denom for its q
  const int b = bh / 12, hd = bh - (bh / 12) * 12;
#pragma unroll
  for (int g = 0; g < 2; g++) {
    const int qrow = q0w + g * 16 + lane16;
    unsigned short* op = Op + (long long)z * 4096 * 768 +
                         ((long long)b * 2048 + qrow) * 768 + hd * 64 + quad * 4;
#pragma unroll
    for (int dt = 0; dt < 4; dt++) {
      ushort4v cv;
#pragma unroll
      for (int r = 0; r < 4; r++) cv[r] = f2bf(o_acc[g][dt][r]);
      *(ushort4v*)(op + dt * 16) = cv;
    }
    if (quad == 0)
      Sm[(long long)z * 24 * 2048 + bh * 2048 + qrow] = sum_acc[g][0];
  }
}

// ---- combine: ctx_bf16 = (O0 + O1) / (s0 + s1), bf16 partials --------------
__global__ __launch_bounds__(256) void k_comb(const unsigned short* __restrict__ Op,
                                              const float* __restrict__ Sm,
                                              unsigned short* __restrict__ ctx) {
  int i = blockIdx.x * 256 + threadIdx.x;  // 4-elem group index, 786432 total
  const int e = i << 2;
  const int row = e / 768;                 // 0..4095
  const int col = e - row * 768;
  const int bh = (row >> 11) * 12 + (col >> 6);
  const int s_idx = row & 2047;
  const float s0 = Sm[bh * 2048 + s_idx];
  const float s1 = Sm[24 * 2048 + bh * 2048 + s_idx];
  const float inv = 1.0f / (s0 + s1);
  ushort4v a = ((const ushort4v*)Op)[i];
  ushort4v b = ((const ushort4v*)(Op + 4096ull * 768))[i];
  ushort4v o;
#pragma unroll
  for (int r = 0; r < 4; r++) o[r] = f2bf((bf2f(a[r]) + bf2f(b[r])) * inv);
  ((ushort4v*)ctx)[i] = o;
}

extern "C" void kernel_launch(void* const* d_in, const int* in_sizes, int n_in,
                              void* d_out, int out_size, void* d_ws, size_t ws_size,
                              hipStream_t stream) {
  const float* x = (const float*)d_in[0];
  // d_in[1] attention_mask: masks scaled by +1e-9 -> no-op, dropped
  const float* w_qkv = (const float*)d_in[2];
  const float* b_qkv = (const float*)d_in[3];
  const float* w_proj = (const float*)d_in[4];
  const float* b_proj = (const float*)d_in[5];
  float* out = (float*)d_out;

  char* ws = (char*)d_ws;
  size_t off = 0;
  auto alloc = [&](size_t bytes) {
    void* p = ws + off;
    off += (bytes + 255) & ~(size_t)255;
    return p;
  };
  __hip_bfloat16* Xb = (__hip_bfloat16*)alloc(4096ull * 768 * 2);      // 6.3 MB
  __hip_bfloat16* WqkvT = (__hip_bfloat16*)alloc(2304ull * 768 * 2);   // 3.5 MB
  __hip_bfloat16* WprojT = (__hip_bfloat16*)alloc(768ull * 768 * 2);   // 1.2 MB
  _Float16* Qb = (_Float16*)alloc(3145728ull * 2);                     // 6.3 MB
  _Float16* Kb = (_Float16*)alloc(3145728ull * 2);                     // 6.3 MB
  _Float16* VT = (_Float16*)alloc(3145728ull * 2);                     // 6.3 MB
  __hip_bfloat16* ctx = (__hip_bfloat16*)alloc(4096ull * 768 * 2);     // 6.3 MB
  unsigned short* Opb = (unsigned short*)alloc(2ull * 4096 * 768 * 2); // 12.6 MB
  float* Sm = (float*)alloc(2ull * 24 * 2048 * 4);                     // 0.4 MB

  k_prep<<<5376, 256, 0, stream>>>(x, (unsigned short*)Xb, w_qkv, WqkvT,
                                   w_proj, WprojT);
  k_gemm_bt<0><<<dim3(32, 24), 256, 0, stream>>>(Xb, WqkvT, b_qkv, nullptr,
                                                 Qb, Kb, VT);
  k_attn<<<dim3(16, 24, 2), 256, 0, stream>>>(Qb, Kb, VT, Opb, Sm);
  k_comb<<<3072, 256, 0, stream>>>(Opb, Sm, (unsigned short*)ctx);
  k_gemm_bt<1><<<dim3(64, 12), 256, 0, stream>>>(ctx, WprojT, b_proj, out,
                                                 nullptr, nullptr, nullptr);
}